// Round 7
// baseline (192.886 us; speedup 1.0000x reference)
//
#include <hip/hip_runtime.h>

#define KDIM 4096   // rows of x (= both i and j extents)
#define NDIM 1024   // feature dim
#define ALPHA 0.2f
#define LOG2E 1.4426950408889634f

typedef _Float16 h2    __attribute__((ext_vector_type(2)));   // packed f16 pair
typedef _Float16 f16x8 __attribute__((ext_vector_type(8)));   // MFMA operand type
typedef __attribute__((ext_vector_type(4))) float f32x4;

// Persistent device scratch. Inputs/outputs f32; internals f16/f32.
// P is never materialized: P_ij = max(E1_j*F1_i, E2_j*F2_i)  (select == max since
// the two lrelu branches cross exactly where they are equal, at t = s1+s2 = 0).
__device__ __align__(16) unsigned short g_xT [(size_t)NDIM * KDIM]; // 8 MB: x^T f16 (n-major, k contiguous)
__device__ __align__(16) float          g_s1L[KDIM];
__device__ __align__(16) float          g_s2L[KDIM];
__device__ __align__(16) unsigned short g_E1h[KDIM];   // f16 bits: exp2(s2L_j)
__device__ __align__(16) unsigned short g_E2h[KDIM];   // f16 bits: exp2(ALPHA*s2L_j)
__device__ __align__(16) unsigned int   g_Fh [KDIM];   // packed (F1_i, F2_i) f16 bits
__device__ __align__(16) float          g_rZ [KDIM];

__device__ __forceinline__ unsigned short f2h(float f){
  _Float16 h = (_Float16)f;
  return *(unsigned short*)&h;
}

// ---- kernel 1: s1L/s2L = (x @ w1, x @ w2) * log2(e).  One wave per row. ----
__global__ __launch_bounds__(256) void k_dots(const float* __restrict__ x,
                                              const float* __restrict__ w){
  const int wid = threadIdx.x >> 6, lane = threadIdx.x & 63;
  const int row = blockIdx.x * 4 + wid;
  const float* xr = x + (size_t)row * NDIM;
  float d1 = 0.f, d2 = 0.f;
  #pragma unroll
  for (int q = 0; q < 4; ++q){
    const int off = q * 256 + lane * 4;
    float4 X  = *(const float4*)(xr + off);
    float4 W1 = *(const float4*)(w + off);
    float4 W2 = *(const float4*)(w + NDIM + off);
    d1 = fmaf(X.x, W1.x, fmaf(X.y, W1.y, fmaf(X.z, W1.z, fmaf(X.w, W1.w, d1))));
    d2 = fmaf(X.x, W2.x, fmaf(X.y, W2.y, fmaf(X.z, W2.z, fmaf(X.w, W2.w, d2))));
  }
  #pragma unroll
  for (int m = 32; m >= 1; m >>= 1){
    d1 += __shfl_xor(d1, m, 64);
    d2 += __shfl_xor(d2, m, 64);
  }
  if (lane == 0){
    g_s1L[row] = d1 * LOG2E;
    g_s2L[row] = d2 * LOG2E;
  }
}

// ---- kernel 2: per-row F1/F2/rZ; block 0 also writes E1h/E2h. ----
// Every block recomputes m2 = max(s2L) from global (16 KB, L2-hit) — removes the
// serial one-block k_escan dispatch of round 5.
__global__ __launch_bounds__(256) void k_zf(){
  __shared__ __align__(16) float s2[KDIM];      // 16 KB
  __shared__ float red[256];
  const int tid = threadIdx.x;
  float mx = -3.0e38f;
  {
    int i = tid * 4;
    #pragma unroll
    for (int c = 0; c < 4; ++c, i += 1024){
      float4 v = *(const float4*)&g_s2L[i];
      *(float4*)&s2[i] = v;
      mx = fmaxf(mx, fmaxf(fmaxf(v.x, v.y), fmaxf(v.z, v.w)));
    }
  }
  red[tid] = mx;
  __syncthreads();
  #pragma unroll
  for (int s = 128; s >= 1; s >>= 1){
    if (tid < s) red[tid] = fmaxf(red[tid], red[tid + s]);
    __syncthreads();
  }
  const float m2 = red[0];

  const int wid = tid >> 6, lane = tid & 63;
  const int row = blockIdx.x * 4 + wid;
  const float s1 = g_s1L[row];
  const float t  = s1 + m2;
  const float mL = fmaxf(t, ALPHA * t);          // lrelu in log2 space
  const float F1 = __builtin_amdgcn_exp2f(s1 - mL);
  const float F2 = __builtin_amdgcn_exp2f(fmaf(ALPHA, s1, -mL));
  float z = 0.f;
  #pragma unroll 8
  for (int c = 0; c < 64; ++c){
    const float s = s2[c * 64 + lane];
    z += fmaxf(__builtin_amdgcn_exp2f(s) * F1,
               __builtin_amdgcn_exp2f(ALPHA * s) * F2);
  }
  #pragma unroll
  for (int m = 32; m >= 1; m >>= 1) z += __shfl_xor(z, m, 64);
  if (lane == 0){
    g_rZ[row] = 1.0f / z;
    g_Fh[row] = (unsigned int)f2h(F1) | ((unsigned int)f2h(F2) << 16);
  }

  if (blockIdx.x == 0){
    for (int j = tid; j < KDIM; j += 256){
      const float s = s2[j];
      g_E1h[j] = f2h(__builtin_amdgcn_exp2f(s));
      g_E2h[j] = f2h(__builtin_amdgcn_exp2f(ALPHA * s));
    }
  }
}

// ---- kernel 3: transpose+convert x (f32, j-major) -> g_xT (f16, n-major). ----
__global__ __launch_bounds__(256) void k_transpose(const float* __restrict__ x){
  __shared__ __align__(16) unsigned short T[64][80];  // 160B rows: 16B-aligned
  const int n0 = blockIdx.x * 64, j0 = blockIdx.y * 64;
  const int tid = threadIdx.x;
  #pragma unroll
  for (int it = 0; it < 4; ++it){
    const int idx = it * 256 + tid;
    const int r = idx >> 4, c4 = idx & 15;
    float4 v = *(const float4*)(x + (size_t)(j0 + r) * NDIM + n0 + c4 * 4);
    T[c4 * 4 + 0][r] = f2h(v.x);
    T[c4 * 4 + 1][r] = f2h(v.y);
    T[c4 * 4 + 2][r] = f2h(v.z);
    T[c4 * 4 + 3][r] = f2h(v.w);
  }
  __syncthreads();
  #pragma unroll
  for (int it = 0; it < 2; ++it){
    const int idx = it * 256 + tid;
    const int n = idx >> 3, cb = idx & 7;
    uint4 u = *(const uint4*)&T[n][cb * 8];
    *(uint4*)(g_xT + (size_t)(n0 + n) * KDIM + j0 + cb * 8) = u;
  }
}

// ---- kernel 4: h = (P @ x) * rZ, A generated in-register (packed f16 max-form). ----
// Block 64m x 128n, 128 threads = 2 waves stacked in m; wave-tile 32m x 128n
// (2 A-frags x 8 B-frags per ks -> each B-frag LDS read feeds 2 MFMAs).
// LDS holds ONLY the double-buffered B tile (2 x 16 KB) -> 2 blocks/CU.
// E1/E2 come from global (L2) into registers, prefetched one kt ahead.
// Grid 512 1-D; n-block = bid&7 pins each xT slice to one XCD's L2.
__global__ __launch_bounds__(128) void k_gemm(float* __restrict__ out){
  __shared__ __align__(16) unsigned short Bb[2][8192]; // 2 x 16 KB (f16)
  const int tid  = threadIdx.x;
  const int w    = tid >> 6, lane = tid & 63;
  const int quad = lane >> 4, l15 = lane & 15;
  const int bid  = blockIdx.x;
  const int n0 = (bid & 7) * 128;
  const int m0 = (bid >> 3) * 64 + w * 32;
  const int srow = lane >> 3, sblk = (lane & 7) ^ srow;   // glds XOR bank swizzle

  // Per-lane F splats for the two m-frags (rows m0+l15, m0+16+l15)
  h2 F1s[2], F2s[2];
  #pragma unroll
  for (int mf = 0; mf < 2; ++mf){
    const unsigned int fb = g_Fh[m0 + mf * 16 + l15];
    const h2 fp = *(const h2*)&fb;
    F1s[mf] = (h2){fp.x, fp.x};
    F2s[mf] = (h2){fp.y, fp.y};
  }

  f32x4 acc[2][8] = {};
  uint4 e1r[2][2], e2r[2][2];   // [kt-parity][ks] : 8 f16 each

  auto stage = [&](int kt, int buf){
    const unsigned short* base = g_xT + (size_t)n0 * KDIM + kt * 64;
    #pragma unroll
    for (int c = 0; c < 8; ++c){
      const int ca = w * 8 + c;                 // chunk 0..15 (8 n-rows each)
      const int r  = ca * 8 + srow;
      const unsigned short* gp = base + (size_t)r * KDIM + sblk * 8;
      __builtin_amdgcn_global_load_lds((const __attribute__((address_space(1))) void*)gp,
          (__attribute__((address_space(3))) void*)(&Bb[buf][ca * 512]), 16, 0, 0);
    }
  };
  auto ldE = [&](int kt, int p){
    const int kb = kt * 64 + quad * 8;          // quad-uniform broadcast reads
    e1r[p][0] = *(const uint4*)(g_E1h + kb);
    e1r[p][1] = *(const uint4*)(g_E1h + kb + 32);
    e2r[p][0] = *(const uint4*)(g_E2h + kb);
    e2r[p][1] = *(const uint4*)(g_E2h + kb + 32);
  };

  stage(0, 0); ldE(0, 0);
  for (int kt = 0; kt < 64; ++kt){
    __syncthreads();                            // drains this iter's staged buffer
    if (kt + 1 < 64){ stage(kt + 1, (kt + 1) & 1); ldE(kt + 1, (kt + 1) & 1); }
    const int p = kt & 1;
    #pragma unroll
    for (int ks = 0; ks < 2; ++ks){
      union { h2 h[4]; f16x8 v; } af[2];
      const h2* E1p = (const h2*)&e1r[p][ks];
      const h2* E2p = (const h2*)&e2r[p][ks];
      #pragma unroll
      for (int jp = 0; jp < 4; ++jp){
        #pragma unroll
        for (int mf = 0; mf < 2; ++mf)
          af[mf].h[jp] = __builtin_elementwise_max(E1p[jp] * F1s[mf],
                                                   E2p[jp] * F2s[mf]);
      }
      #pragma unroll
      for (int nf = 0; nf < 8; ++nf){
        const int n = nf * 16 + l15;
        const int lbq = ((ks << 2) + quad) ^ (n & 7);   // XOR-deswizzle k-block
        const f16x8 bfr = *(const f16x8*)((const char*)&Bb[p][0] + n * 128 + lbq * 16);
        acc[0][nf] = __builtin_amdgcn_mfma_f32_16x16x32_f16(af[0].v, bfr, acc[0][nf], 0, 0, 0);
        acc[1][nf] = __builtin_amdgcn_mfma_f32_16x16x32_f16(af[1].v, bfr, acc[1][nf], 0, 0, 0);
      }
    }
  }

  // epilogue: scale by 1/Z_i. C/D layout: col=lane&15, row=quad*4+reg.
  #pragma unroll
  for (int mf = 0; mf < 2; ++mf){
    #pragma unroll
    for (int r = 0; r < 4; ++r){
      const int row = m0 + mf * 16 + quad * 4 + r;
      const float rz = g_rZ[row];
      #pragma unroll
      for (int nf = 0; nf < 8; ++nf)
        out[(size_t)row * NDIM + n0 + nf * 16 + l15] = acc[mf][nf][r] * rz;
    }
  }
}

extern "C" void kernel_launch(void* const* d_in, const int* in_sizes, int n_in,
                              void* d_out, int out_size, void* d_ws, size_t ws_size,
                              hipStream_t stream){
  const float* x = (const float*)d_in[0];   // f32 (4096x1024)
  const float* w = (const float*)d_in[1];   // f32 (2048)
  float* out = (float*)d_out;               // f32 (4096x1024)
  (void)in_sizes; (void)n_in; (void)out_size; (void)d_ws; (void)ws_size;

  k_dots     <<<dim3(1024),   dim3(256), 0, stream>>>(x, w);
  k_zf       <<<dim3(1024),   dim3(256), 0, stream>>>();
  k_transpose<<<dim3(16, 64), dim3(256), 0, stream>>>(x);
  k_gemm     <<<dim3(512),    dim3(128), 0, stream>>>(out);
}